// Round 6
// baseline (129.738 us; speedup 1.0000x reference)
//
#include <hip/hip_runtime.h>

// Chamfer loss between subsampled point clouds — fused 2-dispatch version.
// srcA: (64000,2) fp32 -> A = 8000 pts  (fp32 linspace trunc, matches jnp)
// srcB: (80000,2) fp32 -> B = 10000 pts
// out  = 0.5 * ( mean_i min_j |A_i - B_j| + mean_j min_i |A_i - B_j| )
//
// Round-4 post-mortem: CHUNK=64 partial-tiling re-gathered each row 157x as
// scattered 8B loads and amortized the block prologue over only ~1.3us of
// hot loop -> chamfer ran 2-4x its VALU floor. Accounting also shows
// ~10-15us of inter-dispatch gaps. Fix: pack once, fuse everything else.
//
//  1) pack_init: subsample ONCE into packed PA/PB = (2x, 2y, -|p|^2, |p|^2)
//     (288 KB, L2-resident); init rowmin[18000]=+inf bits and ticket.
//  2) chamfer_fused: 511 blocks (~2/CU). Block = (2048-row group, 157-col
//     slice). Rows: coalesced from packed. Cols: wave-uniform float4
//     broadcast reads from L1 (NO LDS in hot loop -> no DS-pipe co-limit).
//     Inner op (expanded form): M = fmax(M, fma(px,qx, fma(py,qy, -|q|^2)))
//     = 3 VALU/pair -> ~6.8us hot wall. Result: clamped min-d^2 via
//     uint atomicMin (non-neg floats: uint order == float order; clamp
//     before min == clamp after min since fmax(0,.) monotone).
//     threadfence+ticket: last finishing block reduces the 18000 rowmins
//     (agent-scope loads) -> sqrt -> scaled deterministic sum -> *out.
//     No partial workspace, no third dispatch.
//
// (Round 5 was an infra failure — container died twice, same signature as
//  round 3 which passed unmodified on resubmit. Source re-audited: no
//  spin-waits, no graph-capture violations, all bounds guarded.
//  Resubmitting the same experiment.)

#define SRC_A 64000
#define SRC_B 80000
#define NA 8000
#define NB 10000
#define NTOT (NA + NB)

#define BLOCK 256
#define RPT 8
#define RPB (BLOCK * RPT)      // 2048 rows per block
#define SLICE 157              // cols per block

#define G1 4                   // ceil(NA/RPB)   row-groups, pass 1 (A rows)
#define S1 64                  // ceil(NB/SLICE) col-slices, pass 1 (B cols)
#define G2 5                   // ceil(NB/RPB)   row-groups, pass 2 (B rows)
#define S2 51                  // ceil(NA/SLICE) col-slices, pass 2 (A cols)
#define NBLK1 (G1 * S1)        // 256
#define NBLK2 (G2 * S2)        // 255
#define NBLK (NBLK1 + NBLK2)   // 511  (~2 blocks/CU, balanced)

#define DELTA_A ((float)(SRC_A - 1) / (float)(NA - 1))
#define DELTA_B ((float)(SRC_B - 1) / (float)(NB - 1))

// ws layout:
//   PA     float4[NA]    @ 0          packed A: (2x, 2y, -|p|^2, |p|^2)
//   PB     float4[NB]    @ NA
//   rowmin uint[NTOT]    @ (NA+NB)*4 floats   bits of clamped min d^2
//   done   uint          @ rowmin + NTOT
#define ROWMIN_OFF (NTOT * 4)  // in floats

__global__ __launch_bounds__(BLOCK) void pack_init(
        const float2* __restrict__ srcA, const float2* __restrict__ srcB,
        float* __restrict__ ws) {
    float4* PA = reinterpret_cast<float4*>(ws);
    float4* PB = PA + NA;
    unsigned* rowmin = reinterpret_cast<unsigned*>(ws + ROWMIN_OFF);
    unsigned* done = rowmin + NTOT;
    int t = (int)(blockIdx.x * BLOCK + threadIdx.x);
    if (t == 0) *done = 0u;
    if (t < NA) {
        int idx = (int)((float)t * DELTA_A);
        if (idx > SRC_A - 1) idx = SRC_A - 1;
        float2 q = srcA[idx];
        float n2 = fmaf(q.x, q.x, q.y * q.y);
        PA[t] = make_float4(q.x + q.x, q.y + q.y, -n2, n2);
    }
    if (t < NB) {
        int idx = (int)((float)t * DELTA_B);
        if (idx > SRC_B - 1) idx = SRC_B - 1;
        float2 q = srcB[idx];
        float n2 = fmaf(q.x, q.x, q.y * q.y);
        PB[t] = make_float4(q.x + q.x, q.y + q.y, -n2, n2);
    }
    if (t < NTOT) rowmin[t] = 0x7F800000u;  // +inf
}

__global__ __launch_bounds__(BLOCK) void chamfer_fused(
        float* __restrict__ ws, float* __restrict__ out) {
    const float4* PA = reinterpret_cast<const float4*>(ws);
    const float4* PB = PA + NA;
    unsigned* rowmin = reinterpret_cast<unsigned*>(ws + ROWMIN_OFF);
    unsigned* done = rowmin + NTOT;

    const bool p1 = (int)blockIdx.x < NBLK1;
    const float4* rowsP; const float4* colsP; unsigned* rmin;
    int g, s, nrows, ncols;
    if (p1) {
        int f = (int)blockIdx.x;
        g = f % G1; s = f / G1;
        rowsP = PA; colsP = PB; rmin = rowmin;
        nrows = NA; ncols = NB;
    } else {
        int f = (int)blockIdx.x - NBLK1;
        g = f % G2; s = f / G2;
        rowsP = PB; colsP = PA; rmin = rowmin + NA;
        nrows = NB; ncols = NA;
    }

    // rows: coalesced loads from packed array (clamp load, guard the atomic)
    float px[RPT], py[RPT], pp[RPT], M[RPT];
    int r0 = g * RPB + (int)threadIdx.x;
#pragma unroll
    for (int i = 0; i < RPT; ++i) {
        int r = r0 + i * BLOCK;
        int l = r < nrows ? r : nrows - 1;
        float4 f = rowsP[l];
        px[i] = 0.5f * f.x;   // exact: f.x = 2x
        py[i] = 0.5f * f.y;
        pp[i] = f.w;
        M[i] = -__builtin_inff();
    }

    // cols: wave-uniform broadcast reads (one 16B line txn per load, L1-hot)
    int c0 = s * SLICE;
    int ce = c0 + SLICE; if (ce > ncols) ce = ncols;
#pragma unroll 4
    for (int k = c0; k < ce; ++k) {
        float4 q = colsP[k];
#pragma unroll
        for (int i = 0; i < RPT; ++i) {
            M[i] = fmaxf(M[i], fmaf(px[i], q.x, fmaf(py[i], q.y, q.z)));
        }
    }

    // clamped min-d^2 via uint atomicMin (all values >= 0)
#pragma unroll
    for (int i = 0; i < RPT; ++i) {
        int r = r0 + i * BLOCK;
        if (r < nrows) {
            float d2 = fmaxf(pp[i] - M[i], 0.0f);
            atomicMin(rmin + r, __float_as_uint(d2));
        }
    }

    // last-finishing block reduces the rowmins and writes the output
    __threadfence();
    __syncthreads();
    __shared__ unsigned s_ticket;
    if (threadIdx.x == 0)
        s_ticket = __hip_atomic_fetch_add(done, 1u, __ATOMIC_ACQ_REL,
                                          __HIP_MEMORY_SCOPE_AGENT);
    __syncthreads();
    if (s_ticket == NBLK - 1) {
        float acc = 0.0f;
        for (int r = (int)threadIdx.x; r < NTOT; r += BLOCK) {
            unsigned b = __hip_atomic_load(rowmin + r, __ATOMIC_RELAXED,
                                           __HIP_MEMORY_SCOPE_AGENT);
            float d2 = __uint_as_float(b);
            acc += sqrtf(d2) * (r < NA ? (0.5f / (float)NA)
                                       : (0.5f / (float)NB));
        }
        for (int off = 32; off > 0; off >>= 1) acc += __shfl_down(acc, off, 64);
        __shared__ float red[4];
        if ((threadIdx.x & 63) == 0) red[threadIdx.x >> 6] = acc;
        __syncthreads();
        if (threadIdx.x == 0) *out = red[0] + red[1] + red[2] + red[3];
    }
}

extern "C" void kernel_launch(void* const* d_in, const int* in_sizes, int n_in,
                              void* d_out, int out_size, void* d_ws, size_t ws_size,
                              hipStream_t stream) {
    (void)in_sizes; (void)n_in; (void)out_size; (void)ws_size;
    const float2* srcA = (const float2*)d_in[0];  // img_render_points (1000*64*2)
    const float2* srcB = (const float2*)d_in[1];  // ref point cloud (80000*2)
    float* ws = (float*)d_ws;
    float* out = (float*)d_out;

    pack_init<<<(NTOT + BLOCK - 1) / BLOCK, BLOCK, 0, stream>>>(srcA, srcB, ws);
    chamfer_fused<<<NBLK, BLOCK, 0, stream>>>(ws, out);
}

// Round 7
// 78.093 us; speedup vs baseline: 1.6613x; 1.6613x over previous
//
#include <hip/hip_runtime.h>

// Chamfer loss between subsampled point clouds — pack + partial + reduce.
// srcA: (64000,2) fp32 -> A = 8000 pts  (fp32 linspace trunc, matches jnp)
// srcB: (80000,2) fp32 -> B = 10000 pts
// out  = 0.5 * ( mean_i min_j |A_i - B_j| + mean_j min_i |A_i - B_j| )
//
// Round-6 post-mortem: fused kernel's per-row uint atomicMin = ~1M
// device-scope atomics; per-XCD L2s are NOT cross-coherent so each atomic
// is a far-memory RMW (WRITE_SIZE 4008 KB = 1M x 4B, 81us, VALUBusy 13%).
// Atomics reverted. This version recombines only measured-good parts:
//   - pack once (round 4/6): PA/PB = (2x, 2y, -|q|^2, |p|^2), 288 KB,
//     kills the 2.5M scattered subsample gathers of rounds 2-4.
//   - LDS-staged broadcast cols (rounds 0/1): one stage + one barrier per
//     block, ds_read_b128 broadcast (conflict-free) feeds 24 VALU each.
//   - direct-stored partial min-d^2 (rounds 0-4): plain coalesced stores,
//     4.2 MB total, no atomics.
//   - 282-block reduce (round 4, measured fast): 64 rows x 4 chunk-slices,
//     coalesced, LDS cross-slice min, one atomicAdd per block.
//
// Expanded form: argmin_j |p-q_j|^2 == argmax_j (2p.q_j - |q_j|^2);
//   M = fmax(M, fma(px,qx, fma(py,qy, -|q|^2)))  = 3 VALU ops/pair.
// |p|^2 re-added at store; clamp-at-0 + sqrt in the reduce (monotone).

#define SRC_A 64000
#define SRC_B 80000
#define NA 8000
#define NB 10000
#define NTOT (NA + NB)

#define BLOCK 256
#define RPT 8
#define RPB (BLOCK * RPT)      // 2048 rows per block
#define SLICE 157              // cols per block (staged once in LDS)

#define G1 4                   // ceil(NA/RPB)   row-groups, pass 1 (A rows)
#define S1 64                  // ceil(NB/SLICE) col-slices, pass 1 (B cols)
#define G2 5                   // ceil(NB/RPB)   row-groups, pass 2 (B rows)
#define S2 51                  // ceil(NA/SLICE) col-slices, pass 2 (A cols)
#define NBLK1 (G1 * S1)        // 256
#define NBLK2 (G2 * S2)        // 255  -> 511 blocks (~2/CU, balanced)

#define DELTA_A ((float)(SRC_A - 1) / (float)(NA - 1))
#define DELTA_B ((float)(SRC_B - 1) / (float)(NB - 1))

// ws layout (floats):
//   PA float4[NA], PB float4[NB]           @ 0        (72000 floats, 288 KB)
//   P1 float[S1 * 8192]                    @ PART1_OFF (524288 floats, 2 MB)
//   P2 float[S2 * 10240]                   @ PART2_OFF (522240 floats, 2.09 MB)
#define P1_STRIDE RPB4_1
#define RPB4_1 (G1 * RPB)      // 8192
#define RPB4_2 (G2 * RPB)      // 10240
#define PART1_OFF (NTOT * 4)
#define PART2_OFF (PART1_OFF + S1 * RPB4_1)

__global__ __launch_bounds__(BLOCK) void pack_init(
        const float2* __restrict__ srcA, const float2* __restrict__ srcB,
        float* __restrict__ ws, float* __restrict__ out) {
    float4* PA = reinterpret_cast<float4*>(ws);
    float4* PB = PA + NA;
    int t = (int)(blockIdx.x * BLOCK + threadIdx.x);
    if (t == 0) *out = 0.0f;   // init for reduce's atomicAdd
    if (t < NA) {
        int idx = (int)((float)t * DELTA_A);
        if (idx > SRC_A - 1) idx = SRC_A - 1;
        float2 q = srcA[idx];
        float n2 = fmaf(q.x, q.x, q.y * q.y);
        PA[t] = make_float4(q.x + q.x, q.y + q.y, -n2, n2);
    }
    if (t < NB) {
        int idx = (int)((float)t * DELTA_B);
        if (idx > SRC_B - 1) idx = SRC_B - 1;
        float2 q = srcB[idx];
        float n2 = fmaf(q.x, q.x, q.y * q.y);
        PB[t] = make_float4(q.x + q.x, q.y + q.y, -n2, n2);
    }
}

__global__ __launch_bounds__(BLOCK) void chamfer_partial(
        float* __restrict__ ws) {
    const float4* PA = reinterpret_cast<const float4*>(ws);
    const float4* PB = PA + NA;

    const bool p1 = (int)blockIdx.x < NBLK1;
    const float4* rowsP; const float4* colsP; float* P;
    int g, s, nrows, ncols, pstr;
    if (p1) {
        int f = (int)blockIdx.x;
        g = f % G1; s = f / G1;
        rowsP = PA; colsP = PB; nrows = NA; ncols = NB;
        P = ws + PART1_OFF; pstr = RPB4_1;
    } else {
        int f = (int)blockIdx.x - NBLK1;
        g = f % G2; s = f / G2;
        rowsP = PB; colsP = PA; nrows = NB; ncols = NA;
        P = ws + PART2_OFF; pstr = RPB4_2;
    }

    // stage this block's column slice in LDS (one barrier total)
    __shared__ __align__(16) float4 sc[SLICE];
    int c0 = s * SLICE;
    int cw = ncols - c0; if (cw > SLICE) cw = SLICE;
    if ((int)threadIdx.x < cw) sc[threadIdx.x] = colsP[c0 + (int)threadIdx.x];
    __syncthreads();

    // rows: coalesced loads from packed array (clamp load, guard store)
    float px[RPT], py[RPT], pp[RPT], M[RPT];
    int r0 = g * RPB + (int)threadIdx.x;
#pragma unroll
    for (int i = 0; i < RPT; ++i) {
        int r = r0 + i * BLOCK;
        int l = r < nrows ? r : nrows - 1;
        float4 f = rowsP[l];
        px[i] = 0.5f * f.x;   // exact: f.x = 2x
        py[i] = 0.5f * f.y;
        pp[i] = f.w;
        M[i] = -__builtin_inff();
    }

    if (cw == SLICE) {
        // hot path (113 of 115 slices): compile-time trip count
#pragma unroll 4
        for (int k = 0; k < SLICE; ++k) {
            float4 q = sc[k];  // broadcast across the wave: conflict-free
#pragma unroll
            for (int i = 0; i < RPT; ++i)
                M[i] = fmaxf(M[i], fmaf(px[i], q.x, fmaf(py[i], q.y, q.z)));
        }
    } else {
        for (int k = 0; k < cw; ++k) {
            float4 q = sc[k];
#pragma unroll
            for (int i = 0; i < RPT; ++i)
                M[i] = fmaxf(M[i], fmaf(px[i], q.x, fmaf(py[i], q.y, q.z)));
        }
    }

    // plain coalesced stores of partial min d^2 (no atomics)
#pragma unroll
    for (int i = 0; i < RPT; ++i) {
        int r = r0 + i * BLOCK;
        if (r < nrows) P[s * pstr + r] = pp[i] - M[i];
    }
}

// ---- reduce: 64 rows/block x 4 chunk-slices, coalesced, then LDS+shuffle ----
#define RB_ROWS 64
#define RB1 125   // 8000/64 (exact)
#define RB2 157   // ceil(10000/64)

__global__ __launch_bounds__(BLOCK) void reduce_out(const float* __restrict__ ws,
                                                    float* __restrict__ out) {
    int t  = (int)threadIdx.x;
    int rl = t & 63;        // row within block
    int sl = t >> 6;        // chunk-slice 0..3
    const bool p1 = (int)blockIdx.x < RB1;
    const float* P; int nrows, nch, pstr, rbase; float scale;
    if (p1) {
        P = ws + PART1_OFF; nrows = NA; nch = S1; pstr = RPB4_1;
        rbase = (int)blockIdx.x * RB_ROWS;         scale = 0.5f / (float)NA;
    } else {
        P = ws + PART2_OFF; nrows = NB; nch = S2; pstr = RPB4_2;
        rbase = ((int)blockIdx.x - RB1) * RB_ROWS; scale = 0.5f / (float)NB;
    }
    int r = rbase + rl;                 // < pstr (padded); value guarded at use
    int per = (nch + 3) >> 2;
    int cb = sl * per;
    int ce = cb + per; if (ce > nch) ce = nch;

    float mn = __builtin_inff();
#pragma unroll 8
    for (int c = cb; c < ce; ++c) mn = fminf(mn, P[c * pstr + r]);

    __shared__ float red[4][RB_ROWS];
    red[sl][rl] = mn;
    __syncthreads();

    if (t < 64) {
        float m = fminf(fminf(red[0][rl], red[1][rl]),
                        fminf(red[2][rl], red[3][rl]));
        m = fmaxf(m, 0.0f);  // expanded form can round slightly negative
        float v = (r < nrows) ? sqrtf(m) * scale : 0.0f;
        for (int off = 32; off > 0; off >>= 1) v += __shfl_down(v, off, 64);
        if (rl == 0) atomicAdd(out, v);
    }
}

extern "C" void kernel_launch(void* const* d_in, const int* in_sizes, int n_in,
                              void* d_out, int out_size, void* d_ws, size_t ws_size,
                              hipStream_t stream) {
    (void)in_sizes; (void)n_in; (void)out_size; (void)ws_size;
    const float2* srcA = (const float2*)d_in[0];  // img_render_points (1000*64*2)
    const float2* srcB = (const float2*)d_in[1];  // ref point cloud (80000*2)
    float* ws = (float*)d_ws;
    float* out = (float*)d_out;

    pack_init<<<(NTOT + BLOCK - 1) / BLOCK, BLOCK, 0, stream>>>(srcA, srcB, ws, out);
    chamfer_partial<<<NBLK1 + NBLK2, BLOCK, 0, stream>>>(ws);
    reduce_out<<<RB1 + RB2, BLOCK, 0, stream>>>(ws, out);
}